// Round 24
// baseline (1734.003 us; speedup 1.0000x reference)
//
#include <hip/hip_runtime.h>
#include <utility>

// Problem constants
// DIM_IN=128, DIM_OUT=128, DIM_X=256, L=256, BATCH=8192, fp32 everywhere.
#define NB 8192

// ---------- static_for helper (compile-time register indices) ----------
template <typename F, size_t... I>
__device__ __forceinline__ void sfor_impl(F&& f, std::index_sequence<I...>) {
  (f(std::integral_constant<int, (int)I>{}), ...);
}
template <int N, typename F>
__device__ __forceinline__ void sfor(F&& f) {
  sfor_impl((F&&)f, std::make_index_sequence<N>{});
}

// packed-column-triangle offset: column li holds D[l2][li], l2=li+1..63, padded to x4
constexpr int coff(int li) {
  int o = 0;
  for (int j = 0; j < li; ++j) o += ((63 - j) + 3) & ~3;
  return o;
}
#define CPACK_STRIDE 2176  // > coff(63), float4-aligned

// fast reciprocal: v_rcp_f32 + one Newton step (~1 ulp).
__device__ __forceinline__ float fast_rcp(float x) {
  float r = __builtin_amdgcn_rcpf(x);
  return r * (2.0f - x * r);
}

// fast tanh: 1 - 2/(exp(2x)+1). Clamp keeps e finite.
__device__ __forceinline__ float fast_tanh(float x) {
  const float e = __expf(2.0f * fminf(x, 40.0f));
  return 1.0f - 2.0f * fast_rcp(e + 1.0f);
}

// =================== device functions ===================
// R22 lesson: grid-wide sync flushes the 8 non-coherent XCD L2s (1060us) --
// NEVER use cooperative phasing here. This round exploits the OPPOSITE property:
// the batch chain (T/du/scan/upd) is 100% b-column-local, so one kernel with
// per-block __syncthreads covers it; the solve chain runs as ONE block beside
// it (its stages communicate through same-CU caches + block barriers only).

// ---------- prep: cx[l] = C1[l,:]·x ; xF[k] = Fm[k,:]·x ; rLam = 1/Lam ----------
__device__ void dev_prep(const float* __restrict__ x, const float* __restrict__ C1,
                         const float* __restrict__ Fm, const float* __restrict__ Lam,
                         float* __restrict__ cx, float* __restrict__ xF,
                         float* __restrict__ rLam, int t) {
  float s1 = 0.f, s2 = 0.f;
  for (int i = 0; i < 256; ++i) {
    const float xi = x[i];
    s1 += C1[t * 256 + i] * xi;
    s2 += Fm[t * 256 + i] * xi;
  }
  cx[t] = s1;
  xF[t] = s2;
  rLam[t] = 1.0f / Lam[t];
}

// ---------- blocked-panel GJ inverse of 128x128, 512 threads (sm-pool form) ----
// sm layout: PC [128][20] @0, MB [128][20] @2560, AR [16][132] @5120,
// IV [16*20] @7232 (7552 floats). Verified math (ran correct in R22).
__device__ void dev_inv(float* __restrict__ sm, const float* __restrict__ srcT,
                        int ld, float* __restrict__ dstT, int tid, int s0, int s1) {
  float* PC = sm;
  float* MBp = sm + 2560;
  float* AR = sm + 5120;
  float* IV = sm + 7232;
  const int ti = tid >> 5;
  const int tj = tid & 31;
  const int R = ti * 8, C = tj * 4;
  float a[8][4];
#pragma unroll
  for (int j = 0; j < 4; ++j)
#pragma unroll
    for (int g = 0; g < 2; ++g) {
      const float4 v = *(const float4*)&srcT[(C + j) * ld + (R + 4 * g)];
      a[4 * g + 0][j] = v.x; a[4 * g + 1][j] = v.y;
      a[4 * g + 2][j] = v.z; a[4 * g + 3][j] = v.w;
    }

  for (int s = s0; s < s1; ++s) {
    if ((tj >> 2) == s) {
      const int c0 = C - 16 * s;
#pragma unroll
      for (int i = 0; i < 8; ++i)
        *(float4*)&PC[(R + i) * 20 + c0] =
            make_float4(a[i][0], a[i][1], a[i][2], a[i][3]);
    }
    if ((ti >> 1) == s) {
      const int r0 = R - 16 * s;
#pragma unroll
      for (int i = 0; i < 8; ++i)
        *(float4*)&AR[(r0 + i) * 132 + C] =
            make_float4(a[i][0], a[i][1], a[i][2], a[i][3]);
    }
    __syncthreads();

    if (tid < 16) {
      float q[16];
#pragma unroll
      for (int g = 0; g < 4; ++g) {
        const float4 v = *(const float4*)&PC[(s * 16 + tid) * 20 + 4 * g];
        q[4 * g] = v.x; q[4 * g + 1] = v.y; q[4 * g + 2] = v.z; q[4 * g + 3] = v.w;
      }
#pragma unroll
      for (int kk = 0; kk < 16; ++kk) {
        float ps[16];
#pragma unroll
        for (int j = 0; j < 16; ++j)
          ps[j] = __int_as_float(
              __builtin_amdgcn_readlane(__float_as_int(q[j]), kk));
        const float piv = fast_rcp(ps[kk]);
#pragma unroll
        for (int j = 0; j < 16; ++j) ps[j] = (j == kk) ? piv : ps[j] * piv;
        const bool isP = (tid == kk);
        const float te = isP ? -1.0f : q[kk];
#pragma unroll
        for (int j = 0; j < 16; ++j) {
          const float base = (isP || j == kk) ? 0.0f : q[j];
          q[j] = base - te * ps[j];
        }
      }
#pragma unroll
      for (int g = 0; g < 4; ++g)
        *(float4*)&IV[tid * 20 + 4 * g] =
            make_float4(q[4 * g], q[4 * g + 1], q[4 * g + 2], q[4 * g + 3]);
    }
    __syncthreads();

    {
      const int r = tid & 127, h = tid >> 7;
      float4 mv;
      if ((r >> 4) == s) {
        mv = *(const float4*)&IV[(r & 15) * 20 + 4 * h];
      } else {
        mv = make_float4(0.f, 0.f, 0.f, 0.f);
#pragma unroll
        for (int g = 0; g < 4; ++g) {
          const float4 p = *(const float4*)&PC[r * 20 + 4 * g];
          const float pc[4] = {p.x, p.y, p.z, p.w};
#pragma unroll
          for (int q = 0; q < 4; ++q) {
            const float4 d = *(const float4*)&IV[(4 * g + q) * 20 + 4 * h];
            mv.x -= pc[q] * d.x; mv.y -= pc[q] * d.y;
            mv.z -= pc[q] * d.z; mv.w -= pc[q] * d.w;
          }
        }
      }
      *(float4*)&MBp[r * 20 + 4 * h] = mv;
    }
    __syncthreads();

    if ((tj >> 2) == s) {
      const int c0 = C - 16 * s;
#pragma unroll
      for (int i = 0; i < 8; ++i) {
        const float4 m = *(const float4*)&MBp[(R + i) * 20 + c0];
        a[i][0] = m.x; a[i][1] = m.y; a[i][2] = m.z; a[i][3] = m.w;
      }
    } else {
      if ((ti >> 1) == s) {
#pragma unroll
        for (int i = 0; i < 8; ++i)
#pragma unroll
          for (int j = 0; j < 4; ++j) a[i][j] = 0.f;
      }
#pragma unroll
      for (int half = 0; half < 2; ++half) {
        float4 ar[8];
#pragma unroll
        for (int k = 0; k < 8; ++k)
          ar[k] = *(const float4*)&AR[(half * 8 + k) * 132 + C];
#pragma unroll
        for (int i = 0; i < 8; ++i) {
          const float4 m0 = *(const float4*)&MBp[(R + i) * 20 + half * 8];
          const float4 m1 = *(const float4*)&MBp[(R + i) * 20 + half * 8 + 4];
          const float mi[8] = {m0.x, m0.y, m0.z, m0.w, m1.x, m1.y, m1.z, m1.w};
#pragma unroll
          for (int k = 0; k < 8; ++k) {
            a[i][0] += mi[k] * ar[k].x;
            a[i][1] += mi[k] * ar[k].y;
            a[i][2] += mi[k] * ar[k].z;
            a[i][3] += mi[k] * ar[k].w;
          }
        }
      }
    }
    __syncthreads();
  }
#pragma unroll
  for (int j = 0; j < 4; ++j)
#pragma unroll
    for (int g = 0; g < 2; ++g)
      *(float4*)&dstT[(C + j) * 128 + (R + 4 * g)] = make_float4(
          a[4 * g + 0][j], a[4 * g + 1][j], a[4 * g + 2][j], a[4 * g + 3][j]);
}

// ---------- transpose u: block bb owns b in [bb*64, bb*64+64)  (UNCHANGED) ------
__device__ void dev_T(float* __restrict__ sm, const float* __restrict__ u,
                      float* __restrict__ vw, int bid, int t) {
  const int b0 = bid * 64;
#pragma unroll
  for (int h = 0; h < 2; ++h) {
#pragma unroll
    for (int q = 0; q < 8; ++q) {
      const int idx = q * 512 + t;
      const int bl = idx >> 6;
      const int i2 = idx & 63;
      sm[i2 * 65 + bl] = u[(b0 + bl) * 128 + 64 * h + i2];
    }
    __syncthreads();
#pragma unroll
    for (int q = 0; q < 8; ++q) {
      const int idx = q * 512 + t;
      const int i2 = idx >> 6;
      const int bl = idx & 63;
      vw[(256 + 64 * h + i2) * NB + b0 + bl] = sm[i2 * 65 + bl];
    }
    __syncthreads();
  }
}

// ---------- du, 64-column tile: vw[l][b] = cx[l] + D12[l,:]·u^T[:,b] ----------
// cx computed redundantly per block (same i-ascending order as dev_prep ->
// bit-identical). sm: xl@0(256), cxl@256(256), ut4@512(512 fl), Dl@1024(2048).
__device__ void dev_du64(float* __restrict__ sm, const float* __restrict__ D12,
                         const float* __restrict__ C1, const float* __restrict__ x,
                         float* __restrict__ vw, int bb, int t) {
  float* xl = sm;
  float* cxl = sm + 256;
  float4* ut4 = (float4*)(sm + 512);
  float* Dl = sm + 1024;
  if (t < 256) xl[t] = x[t];
  __syncthreads();
  if (t < 256) {
    float s = 0.f;
    for (int i = 0; i < 256; ++i) s += C1[t * 256 + i] * xl[i];
    cxl[t] = s;
  }
  __syncthreads();
  const float4* vw4 = (const float4*)vw;
  float4* vw4o = (float4*)vw;
  const int col = t & 15;
  const int lg = t >> 4;  // 0..31, l-rows lg*8..lg*8+7
  float4 acc[8];
#pragma unroll
  for (int j = 0; j < 8; ++j) {
    const float c = cxl[lg * 8 + j];
    acc[j] = make_float4(c, c, c, c);
  }
  for (int kc = 0; kc < 16; ++kc) {
    __syncthreads();
    if (t < 128)
      ut4[t] = vw4[(256 + kc * 8 + (t >> 4)) * 2048 + bb * 16 + (t & 15)];
#pragma unroll
    for (int q = 0; q < 4; ++q) {
      const int e = q * 512 + t;  // l = e>>3, i2 = e&7
      Dl[e] = D12[(e >> 3) * 128 + kc * 8 + (e & 7)];
    }
    __syncthreads();
#pragma unroll
    for (int i2 = 0; i2 < 8; ++i2) {
      const float4 w = ut4[i2 * 16 + col];
#pragma unroll
      for (int j = 0; j < 8; ++j) {
        const float d = Dl[(lg * 8 + j) * 8 + i2];
        acc[j].x += d * w.x;
        acc[j].y += d * w.y;
        acc[j].z += d * w.z;
        acc[j].w += d * w.w;
      }
    }
  }
#pragma unroll
  for (int j = 0; j < 8; ++j) vw4o[(lg * 8 + j) * 2048 + bb * 16 + col] = acc[j];
}

// ---------- scan, 64-column tile: triangle gathered from D11 directly ----------
// (same layout as old cpack; srl = 1.0f/Lam same as prep -> bit-identical)
__device__ void dev_scan64(float* __restrict__ sm, const float* __restrict__ D11,
                           const float* __restrict__ Lam, float* __restrict__ vw,
                           int c, int bb, int t) {
  float* sc = sm;
  float* srl = sm + CPACK_STRIDE;
  {
    int off = 0;
    for (int li = 0; li < 63; ++li) {
      if (t < 63 - li)
        sc[off + t] = D11[(c * 64 + li + 1 + t) * 256 + (c * 64 + li)];
      off += ((63 - li) + 3) & ~3;
    }
  }
  if (t < 64) srl[t] = 1.0f / Lam[c * 64 + t];
  __syncthreads();
  if (t < 64) {
    const int b = bb * 64 + t;
    const int l0 = c * 64;
    const float4* cp4 = (const float4*)sc;
    float v[64];
#pragma unroll
    for (int li = 0; li < 64; ++li) v[li] = vw[(l0 + li) * NB + b];
    sfor<64>([&](auto LI) {
      constexpr int li = decltype(LI)::value;
      const float w = fast_tanh(v[li] * srl[li]);
      vw[(l0 + li) * NB + b] = w;
      constexpr int n = 63 - li;
      constexpr int off4 = coff(li) / 4;
      sfor<(n + 3) / 4>([&](auto Q) {
        constexpr int q = decltype(Q)::value;
        const float4 d = cp4[off4 + q];
        if constexpr (4 * q + 0 < n) v[li + 1 + 4 * q + 0] += d.x * w;
        if constexpr (4 * q + 1 < n) v[li + 1 + 4 * q + 1] += d.y * w;
        if constexpr (4 * q + 2 < n) v[li + 1 + 4 * q + 2] += d.z * w;
        if constexpr (4 * q + 3 < n) v[li + 1 + 4 * q + 3] += d.w * w;
      });
    });
  }
  __syncthreads();
}

// ---------- rank-64 update, 64-column tile (k ascending -> bit-identical) ------
// sm: wlds = 1024 float4 (w-chunk rows c*64..+64 x 16 f4 cols).
__device__ void dev_upd64(float* __restrict__ sm, const float* __restrict__ D11,
                          float* __restrict__ vw, int c, int bb, int t) {
  float4* wlds = (float4*)sm;
  float4* vw4 = (float4*)vw;
  const int k0 = c * 64;
#pragma unroll
  for (int q = 0; q < 2; ++q) {
    const int e = q * 512 + t;  // r = e>>4, col = e&15
    wlds[e] = vw4[(k0 + (e >> 4)) * 2048 + bb * 16 + (e & 15)];
  }
  __syncthreads();
  const int col = t & 15;
  const int rb = t >> 4;  // 0..31
  const int r0 = (c + 1) * 64;
  for (int row = r0 + rb; row < 256; row += 32) {
    float4 acc = vw4[row * 2048 + bb * 16 + col];
    for (int k = 0; k < 64; ++k) {
      const float d = D11[row * 256 + k0 + k];
      const float4 w = wlds[k * 16 + col];
      acc.x += d * w.x;
      acc.y += d * w.y;
      acc.z += d * w.z;
      acc.w += d * w.w;
    }
    vw4[row * 2048 + bb * 16 + col] = acc;
  }
  __syncthreads();
}

// ---------- small GEMMs of the solve chain (verbatim bodies, gid-strided) ------
__device__ void dev_WZ(const float* __restrict__ E, const float* __restrict__ C2,
                       const float* __restrict__ inv1T, float* __restrict__ W,
                       float* __restrict__ z1, int gid) {
  const int half = gid >> 14;
  const int idx = gid & 16383;
  const int j = idx >> 7;
  const int i = idx & 127;
  float s = 0.f;
  if (half == 0) {
    for (int m = 0; m < 128; ++m) s += inv1T[m * 128 + i] * E[(128 + j) * 256 + m];
    W[i * 128 + j] = s;
  } else {
    for (int m = 0; m < 128; ++m) s += inv1T[m * 128 + i] * C2[j * 256 + m];
    z1[i * 128 + j] = s;
  }
}

__device__ void dev_SC(const float* __restrict__ E, const float* __restrict__ C2,
                       const float* __restrict__ W, const float* __restrict__ z1,
                       float* __restrict__ STt, float* __restrict__ c2p, int gid) {
  if (gid < 16384) {
    const int jj = gid >> 7;
    const int i = gid & 127;
    float s = E[(128 + jj) * 256 + 128 + i];
    for (int m = 0; m < 128; ++m) s -= E[m * 256 + 128 + i] * W[m * 128 + jj];
    STt[jj * 128 + i] = s;
  } else {
    const int idx = gid - 16384;
    const int i = idx >> 7;
    const int o = idx & 127;
    float s = C2[o * 256 + 128 + i];
    for (int m = 0; m < 128; ++m) s -= E[m * 256 + 128 + i] * z1[m * 128 + o];
    c2p[i * 128 + o] = s;
  }
}

__device__ void dev_G2(const float* __restrict__ inv2T, const float* __restrict__ c2p,
                       float* __restrict__ g2, int gid) {
  const int i = gid >> 7;
  const int o = gid & 127;
  float s = 0.f;
  for (int m = 0; m < 128; ++m) s += inv2T[m * 128 + i] * c2p[m * 128 + o];
  g2[i * 128 + o] = s;
}

__device__ void dev_G1(const float* __restrict__ W, const float* __restrict__ z1,
                       const float* __restrict__ g2, float* __restrict__ g1, int gid) {
  const int i = gid >> 7;
  const int o = gid & 127;
  float s = z1[i * 128 + o];
  for (int m = 0; m < 128; ++m) s -= W[i * 128 + m] * g2[m * 128 + o];
  g1[i * 128 + o] = s;
}

__device__ void dev_R(const float* __restrict__ B1, const float* __restrict__ B2,
                      const float* __restrict__ D21, const float* __restrict__ D22,
                      const float* __restrict__ g1, const float* __restrict__ g2,
                      const float* __restrict__ xF, float* __restrict__ R,
                      float* __restrict__ y0, int gid) {
  if (gid < 32768) {
    const int o = gid >> 8;
    const int l = gid & 255;
    float s = D21[o * 256 + l];
    for (int m = 0; m < 128; ++m) {
      s += g1[m * 128 + o] * B1[m * 256 + l];
      s += g2[m * 128 + o] * B1[(128 + m) * 256 + l];
    }
    R[o * 384 + l] = s;
  } else if (gid < 49152) {
    const int t2 = gid - 32768;
    const int o = t2 >> 7;
    const int i = t2 & 127;
    float s = D22[o * 128 + i];
    for (int m = 0; m < 128; ++m) {
      s += g1[m * 128 + o] * B2[m * 128 + i];
      s += g2[m * 128 + o] * B2[(128 + m) * 128 + i];
    }
    R[o * 384 + 256 + i] = s;
  } else if (gid < 49280) {
    const int o = gid - 49152;
    float s = 0.f;
    for (int m = 0; m < 128; ++m) {
      s += g1[m * 128 + o] * xF[m];
      s += g2[m * 128 + o] * xF[128 + m];
    }
    y0[o] = s;
  }
}

// =================== kernel 1: fused batch chain + single-block solve ==========
// Blocks 0..127: batch chain on 64 b-columns each (column-local, block barriers
// only). Block 128: entire solve chain sequentially (same-CU cache coherence +
// block barriers). The two never communicate. k_y's kernel boundary is the fence.
__global__ __launch_bounds__(512) void fused(
    const float* __restrict__ u, const float* __restrict__ x,
    const float* __restrict__ Fm, const float* __restrict__ B1,
    const float* __restrict__ B2, const float* __restrict__ C1,
    const float* __restrict__ C2, const float* __restrict__ D11,
    const float* __restrict__ D12, const float* __restrict__ D21,
    const float* __restrict__ D22, const float* __restrict__ E,
    const float* __restrict__ Lam, float* vw, float* inv1T, float* Wm,
    float* z1, float* STt, float* c2p, float* inv2T, float* g2, float* g1,
    float* Rm, float* y0v, float* cx, float* xF, float* rLam) {
  __shared__ __align__(16) float sm[7552];  // 30.2KB pool (inv is max user)
  const int B = blockIdx.x;
  const int t = threadIdx.x;

  if (B < 128) {
    // ---------------- batch chain, columns [B*64, B*64+64) ----------------
    dev_T(sm, u, vw, B, t);
    __syncthreads();
    dev_du64(sm, D12, C1, x, vw, B, t);
    __syncthreads();
    dev_scan64(sm, D11, Lam, vw, 0, B, t);
    dev_upd64(sm, D11, vw, 0, B, t);
    dev_scan64(sm, D11, Lam, vw, 1, B, t);
    dev_upd64(sm, D11, vw, 1, B, t);
    dev_scan64(sm, D11, Lam, vw, 2, B, t);
    dev_upd64(sm, D11, vw, 2, B, t);
    dev_scan64(sm, D11, Lam, vw, 3, B, t);
  } else {
    // ---------------- solve chain, one block, sequential ----------------
    if (t < 256) dev_prep(x, C1, Fm, Lam, cx, xF, rLam, t);
    __syncthreads();
    dev_inv(sm, E, 256, inv1T, t, 0, 8);
    __syncthreads();
    for (int g = t; g < 32768; g += 512) dev_WZ(E, C2, inv1T, Wm, z1, g);
    __syncthreads();
    for (int g = t; g < 32768; g += 512) dev_SC(E, C2, Wm, z1, STt, c2p, g);
    __syncthreads();
    dev_inv(sm, STt, 128, inv2T, t, 0, 8);
    __syncthreads();
    for (int g = t; g < 16384; g += 512) dev_G2(inv2T, c2p, g2, g);
    __syncthreads();
    for (int g = t; g < 16384; g += 512) dev_G1(Wm, z1, g2, g1, g);
    __syncthreads();
    for (int g = t; g < 49280; g += 512)
      dev_R(B1, B2, D21, D22, g1, g2, xF, Rm, y0v, g);
  }
}

// ---------- y[b][o] = y0[o] + sum_{k<384} R[o][k] vw[k][b]  (R17 verified) -----
__global__ __launch_bounds__(512) void k_y(const float* __restrict__ vw,
                                           const float* __restrict__ R,
                                           const float* __restrict__ y0,
                                           float* __restrict__ y) {
  __shared__ float Rl[1536];
  __shared__ float part[256 * 16];
  const int tid = threadIdx.x;
  const int bid = blockIdx.x;
  const int gx = bid & 7;
  const int gy = bid >> 3;
  const int o0 = gy * 4;
#pragma unroll
  for (int q = 0; q < 3; ++q) Rl[q * 512 + tid] = R[o0 * 384 + q * 512 + tid];
  __syncthreads();

  const int lane = tid & 255;
  const int ks = tid >> 8;
  const int kbase = ks * 192;
  const float4* vw4 = (const float4*)vw;
  const int b4 = gx * 256 + lane;
  float acc[4][4];
#pragma unroll
  for (int j = 0; j < 4; ++j)
#pragma unroll
    for (int bi = 0; bi < 4; ++bi) acc[bi][j] = 0.f;

  for (int k = 0; k < 192; k += 8) {
    float4 w[8];
#pragma unroll
    for (int kk = 0; kk < 8; ++kk) w[kk] = vw4[(kbase + k + kk) * 2048 + b4];
#pragma unroll
    for (int j = 0; j < 4; ++j) {
      const float4 r0 = *(const float4*)&Rl[j * 384 + kbase + k];
      const float4 r1 = *(const float4*)&Rl[j * 384 + kbase + k + 4];
      acc[0][j] += r0.x * w[0].x + r0.y * w[1].x + r0.z * w[2].x + r0.w * w[3].x +
                   r1.x * w[4].x + r1.y * w[5].x + r1.z * w[6].x + r1.w * w[7].x;
      acc[1][j] += r0.x * w[0].y + r0.y * w[1].y + r0.z * w[2].y + r0.w * w[3].y +
                   r1.x * w[4].y + r1.y * w[5].y + r1.z * w[6].y + r1.w * w[7].y;
      acc[2][j] += r0.x * w[0].z + r0.y * w[1].z + r0.z * w[2].z + r0.w * w[3].z +
                   r1.x * w[4].z + r1.y * w[5].z + r1.z * w[6].z + r1.w * w[7].z;
      acc[3][j] += r0.x * w[0].w + r0.y * w[1].w + r0.z * w[2].w + r0.w * w[3].w +
                   r1.x * w[4].w + r1.y * w[5].w + r1.z * w[6].w + r1.w * w[7].w;
    }
  }

  if (ks == 1) {
#pragma unroll
    for (int bi = 0; bi < 4; ++bi)
      *(float4*)&part[lane * 16 + bi * 4] =
          make_float4(acc[bi][0], acc[bi][1], acc[bi][2], acc[bi][3]);
  }
  __syncthreads();
  if (ks == 0) {
    const int b0 = b4 * 4;
#pragma unroll
    for (int bi = 0; bi < 4; ++bi) {
      const float4 p = *(const float4*)&part[lane * 16 + bi * 4];
      *(float4*)&y[(b0 + bi) * 128 + o0] =
          make_float4(acc[bi][0] + p.x + y0[o0 + 0],
                      acc[bi][1] + p.y + y0[o0 + 1],
                      acc[bi][2] + p.z + y0[o0 + 2],
                      acc[bi][3] + p.w + y0[o0 + 3]);
    }
  }
}

extern "C" void kernel_launch(void* const* d_in, const int* in_sizes, int n_in,
                              void* d_out, int out_size, void* d_ws, size_t ws_size,
                              hipStream_t stream) {
  const float* u   = (const float*)d_in[0];   // (8192,1,128)
  const float* x   = (const float*)d_in[1];   // (1,1,256)
  const float* Fm  = (const float*)d_in[2];   // (256,256)
  const float* B1  = (const float*)d_in[3];   // (256,256)
  const float* B2  = (const float*)d_in[4];   // (256,128)
  const float* C1  = (const float*)d_in[5];   // (256,256)
  const float* C2  = (const float*)d_in[6];   // (128,256)
  const float* D11 = (const float*)d_in[7];   // (256,256) strictly lower
  const float* D12 = (const float*)d_in[8];   // (256,128)
  const float* D21 = (const float*)d_in[9];   // (128,256)
  const float* D22 = (const float*)d_in[10];  // (128,128)
  const float* E   = (const float*)d_in[11];  // (256,256)
  const float* Lam = (const float*)d_in[12];  // (256,)
  float* y = (float*)d_out;                   // (8192,1,128) fp32

  float* F = (float*)d_ws;                     // ~13.4 MB used
  float* vw    = F;                            // 384*8192 (rows 256..383 = u^T)
  float* SMb   = F + 384 * NB;
  float* inv1T = SMb;                          // 16384
  float* Wm    = SMb + 16384;
  float* z1    = SMb + 32768;
  float* STt   = SMb + 49152;
  float* c2p   = SMb + 65536;
  float* inv2T = SMb + 81920;
  float* g2    = SMb + 98304;
  float* g1    = SMb + 114688;
  float* Rm    = SMb + 131072;                 // 128*384
  float* y0v   = SMb + 180224;                 // 128
  float* cx    = SMb + 180352;                 // 256
  float* xF    = SMb + 180608;                 // 256
  float* rLam  = SMb + 180864;                 // 256

  fused<<<129, 512, 0, stream>>>(u, x, Fm, B1, B2, C1, C2, D11, D12, D21, D22,
                                 E, Lam, vw, inv1T, Wm, z1, STt, c2p, inv2T,
                                 g2, g1, Rm, y0v, cx, xF, rLam);
  k_y<<<256, 512, 0, stream>>>(vw, Rm, y0v, y);
}